// Round 10
// baseline (567.615 us; speedup 1.0000x reference)
//
#include <hip/hip_runtime.h>

#define NSEG 40000
#define NREG 1000
#define NEDGE 640000
#define HID 256
#define KCAT 1280   // 5 * HID
#define KP1 1024    // padded K stride for Pt (cols 1000..1023 zero)
#define LPAD 40     // LDS row stride (bf16) for gemm1 tiles
#define NBLK 157    // ceil(NSEG/256)

typedef float f32x4 __attribute__((ext_vector_type(4)));
typedef short s16x8 __attribute__((ext_vector_type(8)));
typedef unsigned short u16x4 __attribute__((ext_vector_type(4)));
typedef unsigned short u16x8 __attribute__((ext_vector_type(8)));

typedef __attribute__((address_space(3))) unsigned int lds_u32;
typedef __attribute__((address_space(1))) const unsigned int glb_u32;

__device__ __forceinline__ void dma16(const void* g, void* l) {
    // per-lane GLOBAL src; wave-uniform LDS base, HW writes lane i at base+i*16.
    __builtin_amdgcn_global_load_lds((glb_u32*)g, (lds_u32*)l, 16, 0, 0);
}

__device__ __forceinline__ unsigned short f2bf(float f) {
    unsigned u = __builtin_bit_cast(unsigned, f);
    u += 0x7FFFu + ((u >> 16) & 1u);   // round-to-nearest-even
    return (unsigned short)(u >> 16);
}
__device__ __forceinline__ float bf2f(unsigned short h) {
    unsigned u = ((unsigned)h) << 16;
    return __builtin_bit_cast(float, u);
}

__device__ __forceinline__ f32x4 mfma16(s16x8 a, s16x8 b, f32x4 c) {
    return __builtin_amdgcn_mfma_f32_16x16x32_bf16(a, b, c, 0, 0, 0);
}

// ---------------------------------------------------------------- edge dtype
__global__ void detect_kernel(const unsigned int* __restrict__ E, int* flag) {
    int lane = threadIdx.x;
    unsigned v = E[2 * lane + 1];
    unsigned long long m = __ballot(v == 0u);
    if (lane == 0) *flag = (__popcll(m) >= 48) ? 1 : 0;
}

__device__ __forceinline__ int edge_at(const void* E, int idx, int is64) {
    return is64 ? (int)((const long long*)E)[idx] : ((const int*)E)[idx];
}

// ---------------------------------------------------------------- CSR build
__global__ __launch_bounds__(256) void deg_cnt_kernel(const void* __restrict__ E,
                                                      const int* __restrict__ flag,
                                                      int* deg, int* cnt) {
    int e = blockIdx.x * 256 + threadIdx.x;
    if (e >= NEDGE) return;
    int is64 = *flag;
    int s = edge_at(E, e, is64);
    int d = edge_at(E, e + NEDGE, is64);
    if (s != d) {
        atomicAdd(&deg[s], 1);
        atomicAdd(&cnt[d], 1);
    }
}

__global__ __launch_bounds__(256) void dinv_kernel(const int* __restrict__ deg,
                                                   float* __restrict__ dinv) {
    int i = blockIdx.x * 256 + threadIdx.x;
    if (i < NSEG) {
        int d = deg[i];
        dinv[i] = d > 0 ? rsqrtf((float)d) : 0.f;
    }
}

// --- hierarchical scan
__global__ __launch_bounds__(256) void scan1_kernel(const int* __restrict__ cnt,
                                                    int* __restrict__ bsum) {
    __shared__ int sh[256];
    int t = threadIdx.x;
    int i = blockIdx.x * 256 + t;
    sh[t] = (i < NSEG) ? cnt[i] : 0;
    __syncthreads();
    for (int o = 128; o > 0; o >>= 1) {
        if (t < o) sh[t] += sh[t + o];
        __syncthreads();
    }
    if (t == 0) bsum[blockIdx.x] = sh[0];
}

__global__ __launch_bounds__(256) void scan2_kernel(const int* __restrict__ bsum,
                                                    int* __restrict__ boff,
                                                    int* __restrict__ rowptr) {
    __shared__ int sh[256];
    int t = threadIdx.x;
    int v = (t < NBLK) ? bsum[t] : 0;
    sh[t] = v;
    __syncthreads();
    for (int o = 1; o < 256; o <<= 1) {
        int x = 0;
        if (t >= o) x = sh[t - o];
        __syncthreads();
        if (t >= o) sh[t] += x;
        __syncthreads();
    }
    if (t < NBLK) boff[t] = sh[t] - v;
    if (t == 255) rowptr[NSEG] = sh[255];
}

__global__ __launch_bounds__(256) void scan3_kernel(const int* __restrict__ cnt,
                                                    const int* __restrict__ boff,
                                                    int* __restrict__ rowptr,
                                                    int* __restrict__ cursor) {
    __shared__ int sh[256];
    int t = threadIdx.x;
    int i = blockIdx.x * 256 + t;
    int v = (i < NSEG) ? cnt[i] : 0;
    sh[t] = v;
    __syncthreads();
    for (int o = 1; o < 256; o <<= 1) {
        int x = 0;
        if (t >= o) x = sh[t - o];
        __syncthreads();
        if (t >= o) sh[t] += x;
        __syncthreads();
    }
    if (i < NSEG) {
        int p = boff[blockIdx.x] + sh[t] - v;
        rowptr[i] = p;
        cursor[i] = p;
    }
}

// writes fused (colidx, val-bits) 8B records
__global__ __launch_bounds__(256) void scatter_kernel(const void* __restrict__ E,
                                                      const int* __restrict__ flag,
                                                      const float* __restrict__ dinv,
                                                      int* cursor,
                                                      long long* __restrict__ colval) {
    int e = blockIdx.x * 256 + threadIdx.x;
    if (e >= NEDGE) return;
    int is64 = *flag;
    int s = edge_at(E, e, is64);
    int d = edge_at(E, e + NEDGE, is64);
    if (s != d) {
        int pos = atomicAdd(&cursor[d], 1);
        float v = -dinv[s] * dinv[d];
        colval[pos] = ((long long)(unsigned)__builtin_bit_cast(unsigned, v) << 32)
                    | (unsigned)s;
    }
}

// ---------------------------------------------------------------- weight prep
__global__ void prep_pt_kernel(const float* __restrict__ P, unsigned short* __restrict__ Pt) {
    int n = blockIdx.x;
    for (int k = threadIdx.x; k < KP1; k += blockDim.x)
        Pt[(size_t)n * KP1 + k] = (k < NREG) ? f2bf(P[(size_t)k * HID + n]) : (unsigned short)0;
}
__global__ void prep_wt_kernel(const float* __restrict__ W, unsigned short* __restrict__ Wt) {
    int n = blockIdx.x;
    for (int k = threadIdx.x; k < KCAT; k += blockDim.x)
        Wt[(size_t)n * KCAT + k] = f2bf(W[(size_t)k * HID + n]);
}

// ---------------------------------------------------------------- GEMM1 (R9-exact: 93-96us)
__global__ __launch_bounds__(256) void gemm1_kernel(const float* __restrict__ S,
                                                    const unsigned short* __restrict__ Pt,
                                                    float* __restrict__ raw,
                                                    unsigned short* __restrict__ xcat) {
    __shared__ unsigned short As[64][LPAD];
    __shared__ unsigned short Bs[256][LPAD];
    const int m0 = blockIdx.x * 64;
    const int tid = threadIdx.x;
    const int lane = tid & 63, wn = tid >> 6;
    const int r = lane & 15, q = lane >> 4;
    const int srow = tid >> 2, scol = (tid & 3) * 8;

    f32x4 acc[4][4] = {};

    for (int kb = 0; kb < NREG; kb += 32) {
        const bool kvalid = (kb + scol + 8 <= NREG);  // NREG % 8 == 0
        u16x8 av = {0, 0, 0, 0, 0, 0, 0, 0};
        u16x8 bv0 = av, bv1 = av, bv2 = av, bv3 = av;
        if (kvalid) {
            const float* sp = S + (size_t)(m0 + srow) * NREG + kb + scol;
            f32x4 f0 = *(const f32x4*)sp;
            f32x4 f1 = *(const f32x4*)(sp + 4);
            av[0] = f2bf(f0[0]); av[1] = f2bf(f0[1]); av[2] = f2bf(f0[2]); av[3] = f2bf(f0[3]);
            av[4] = f2bf(f1[0]); av[5] = f2bf(f1[1]); av[6] = f2bf(f1[2]); av[7] = f2bf(f1[3]);
            bv0 = *(const u16x8*)(Pt + (size_t)(srow)       * KP1 + kb + scol);
            bv1 = *(const u16x8*)(Pt + (size_t)(srow +  64) * KP1 + kb + scol);
            bv2 = *(const u16x8*)(Pt + (size_t)(srow + 128) * KP1 + kb + scol);
            bv3 = *(const u16x8*)(Pt + (size_t)(srow + 192) * KP1 + kb + scol);
        }
        __syncthreads();
        *(u16x8*)&As[srow][scol] = av;
        *(u16x8*)&Bs[srow][scol] = bv0;
        *(u16x8*)&Bs[srow + 64][scol] = bv1;
        *(u16x8*)&Bs[srow + 128][scol] = bv2;
        *(u16x8*)&Bs[srow + 192][scol] = bv3;
        __syncthreads();
        s16x8 af[4], bfv[4];
#pragma unroll
        for (int am = 0; am < 4; ++am) af[am] = *(const s16x8*)&As[am * 16 + r][q * 8];
#pragma unroll
        for (int bn = 0; bn < 4; ++bn) bfv[bn] = *(const s16x8*)&Bs[wn * 64 + bn * 16 + r][q * 8];
#pragma unroll
        for (int am = 0; am < 4; ++am) {
#pragma unroll
            for (int bn = 0; bn < 4; ++bn)
                acc[am][bn] = mfma16(af[am], bfv[bn], acc[am][bn]);
        }
    }
#pragma unroll
    for (int am = 0; am < 4; ++am) {
        int rowb = m0 + am * 16 + q * 4;
#pragma unroll
        for (int bn = 0; bn < 4; ++bn) {
            int col = wn * 64 + bn * 16 + r;
#pragma unroll
            for (int i = 0; i < 4; ++i) {
                float v = acc[am][bn][i];
                raw[(size_t)(rowb + i) * HID + col] = v;
                xcat[(size_t)(rowb + i) * KCAT + col] = f2bf(v);
            }
        }
    }
}

// ---------------------------------------------------------------- propagation (column-tiled)
// 4 passes of 64 cols each; pass-major block index phases passes so the
// gather working set per phase is ~5.1 MB (L2-resident). Lane owns 1 col.
__global__ __launch_bounds__(256) void prop_kernel(unsigned short* xcat,
                                                   const int* __restrict__ rowptr,
                                                   const long long* __restrict__ colval,
                                                   int inOff, int outOff, int subOff,
                                                   float scale) {
    const int bid = blockIdx.x;
    const int pass = bid / (NSEG / 4);     // 0..3
    const int ng   = bid % (NSEG / 4);
    const int g = ng * 4 + (threadIdx.x >> 6);
    const int lane = threadIdx.x & 63;
    const int col = pass * 64 + lane;
    const unsigned short* xin = xcat + inOff + col;
    int e0 = rowptr[g], e1 = rowptr[g + 1];
    float a = 0.f;
    for (int base = e0; base < e1; base += 64) {
        int m = e1 - base;
        if (m > 64) m = 64;
        int cc = 0;
        float vv = 0.f;
        if (lane < m) {
            long long cv = colval[base + lane];
            cc = (int)(unsigned)cv;
            vv = __builtin_bit_cast(float, (unsigned)(cv >> 32));
        }
        int i = 0;
        for (; i + 8 <= m; i += 8) {
            float t0, t1, t2, t3, t4, t5, t6, t7;
            {
                int c0 = __shfl(cc, i + 0), c1 = __shfl(cc, i + 1);
                int c2 = __shfl(cc, i + 2), c3 = __shfl(cc, i + 3);
                int c4 = __shfl(cc, i + 4), c5 = __shfl(cc, i + 5);
                int c6 = __shfl(cc, i + 6), c7 = __shfl(cc, i + 7);
                t0 = bf2f(xin[(size_t)c0 * KCAT]);
                t1 = bf2f(xin[(size_t)c1 * KCAT]);
                t2 = bf2f(xin[(size_t)c2 * KCAT]);
                t3 = bf2f(xin[(size_t)c3 * KCAT]);
                t4 = bf2f(xin[(size_t)c4 * KCAT]);
                t5 = bf2f(xin[(size_t)c5 * KCAT]);
                t6 = bf2f(xin[(size_t)c6 * KCAT]);
                t7 = bf2f(xin[(size_t)c7 * KCAT]);
            }
            a += __shfl(vv, i + 0) * t0;
            a += __shfl(vv, i + 1) * t1;
            a += __shfl(vv, i + 2) * t2;
            a += __shfl(vv, i + 3) * t3;
            a += __shfl(vv, i + 4) * t4;
            a += __shfl(vv, i + 5) * t5;
            a += __shfl(vv, i + 6) * t6;
            a += __shfl(vv, i + 7) * t7;
        }
        for (; i < m; ++i) {
            int c = __shfl(cc, i);
            float v = __shfl(vv, i);
            a += v * bf2f(xin[(size_t)c * KCAT]);
        }
    }
    a *= scale;
    if (subOff >= 0) a -= bf2f(xcat[(size_t)g * KCAT + subOff + col]);
    xcat[(size_t)g * KCAT + outOff + col] = f2bf(a);
}

// ---------------------------------------------------------------- GEMM2 + GELU + LN (R9-exact, BM=128 dbuf-DMA)
__global__ __launch_bounds__(512) void gemm2_kernel(const unsigned short* __restrict__ xcat,
                                                    const unsigned short* __restrict__ Wt,
                                                    const float* __restrict__ bias,
                                                    const float* __restrict__ gamma,
                                                    const float* __restrict__ beta,
                                                    float* __restrict__ outp) {
    __shared__ unsigned short As[2][128 * 32];
    __shared__ unsigned short Bs[2][256 * 32];
    __shared__ float rs[128][4];
    __shared__ float rss[128][4];
    const int tid = threadIdx.x;
    const int lane = tid & 63, wid = tid >> 6;
    const int wm = wid >> 2, wn = wid & 3;
    const int r = lane & 15, q = lane >> 4;
    const int qx8 = (q ^ (r & 3)) << 3;
    const int m0 = blockIdx.x * 128;
    const int crow = lane >> 2;
    const int bcol = (((lane & 3) ^ ((lane >> 2) & 3)) << 3);

    f32x4 acc[4][4] = {};

    // 24 chunks/buffer: 0..15 = B (Wt rows), 16..23 = A (xcat rows m0+..).
    auto stage = [&](int c, int kb) {
#pragma unroll
        for (int k = 0; k < 3; ++k) {
            int idx = 3 * wid + k;
            if (idx < 16) {
                int n = idx * 16 + crow;
                dma16(Wt + (size_t)n * KCAT + kb + bcol, &Bs[c][idx * 512]);
            } else {
                int a = idx - 16;
                int row = m0 + a * 16 + crow;   // tail reads past xcat land in ws: safe, store-guarded
                dma16(xcat + (size_t)row * KCAT + kb + bcol, &As[c][a * 512]);
            }
        }
    };

    stage(0, 0);
    __syncthreads();

    for (int t = 0; t < 40; ++t) {
        const int c = t & 1;
        if (t < 39) stage(c ^ 1, (t + 1) * 32);
        s16x8 af[4], bfv[4];
#pragma unroll
        for (int am = 0; am < 4; ++am)
            af[am] = *(const s16x8*)&As[c][(wm * 64 + am * 16 + r) * 32 + qx8];
#pragma unroll
        for (int bn = 0; bn < 4; ++bn)
            bfv[bn] = *(const s16x8*)&Bs[c][(wn * 64 + bn * 16 + r) * 32 + qx8];
#pragma unroll
        for (int am = 0; am < 4; ++am)
#pragma unroll
            for (int bn = 0; bn < 4; ++bn)
                acc[am][bn] = mfma16(af[am], bfv[bn], acc[am][bn]);
        __syncthreads();
    }

    // epilogue: bias + exact GELU, row stats, LN, store
    float bc[4], gm[4], bt[4];
#pragma unroll
    for (int bn = 0; bn < 4; ++bn) {
        int col = wn * 64 + bn * 16 + r;
        bc[bn] = bias[col];
        gm[bn] = gamma[col];
        bt[bn] = beta[col];
    }
#pragma unroll
    for (int am = 0; am < 4; ++am) {
#pragma unroll
        for (int i = 0; i < 4; ++i) {
            float s = 0.f, ss = 0.f;
#pragma unroll
            for (int bn = 0; bn < 4; ++bn) {
                float v = acc[am][bn][i] + bc[bn];
                v = 0.5f * v * (1.f + erff(v * 0.70710678118654752f));
                acc[am][bn][i] = v;
                s += v;
                ss += v * v;
            }
#pragma unroll
            for (int msk = 1; msk < 16; msk <<= 1) {
                s += __shfl_xor(s, msk);
                ss += __shfl_xor(ss, msk);
            }
            if (r == 0) {
                int row = wm * 64 + am * 16 + q * 4 + i;
                rs[row][wn] = s;
                rss[row][wn] = ss;
            }
        }
    }
    __syncthreads();
#pragma unroll
    for (int am = 0; am < 4; ++am) {
#pragma unroll
        for (int i = 0; i < 4; ++i) {
            int row = wm * 64 + am * 16 + q * 4 + i;
            float s = rs[row][0] + rs[row][1] + rs[row][2] + rs[row][3];
            float ss = rss[row][0] + rss[row][1] + rss[row][2] + rss[row][3];
            float mu = s * (1.f / HID);
            float var = ss * (1.f / HID) - mu * mu;
            float inv = rsqrtf(var + 1e-5f);
            if (m0 + row < NSEG) {
#pragma unroll
                for (int bn = 0; bn < 4; ++bn) {
                    int col = wn * 64 + bn * 16 + r;
                    outp[(size_t)(m0 + row) * HID + col] = (acc[am][bn][i] - mu) * inv * gm[bn] + bt[bn];
                }
            }
        }
    }
}

// ---------------------------------------------------------------- launch
extern "C" void kernel_launch(void* const* d_in, const int* in_sizes, int n_in,
                              void* d_out, int out_size, void* d_ws, size_t ws_size,
                              hipStream_t stream) {
    const float* P     = (const float*)d_in[0];
    const float* S     = (const float*)d_in[1];
    const void*  E     = d_in[2];
    const float* W     = (const float*)d_in[3];
    const float* bias  = (const float*)d_in[4];
    const float* gamma = (const float*)d_in[5];
    const float* beta  = (const float*)d_in[6];

    float* out = (float*)d_out;            // seg_low [40000*256]
    float* raw = out + (size_t)NSEG * HID; // seg_low_raw [40000*256]

    char* ws = (char*)d_ws;
    size_t off = 0;
    auto alloc = [&](size_t bytes) -> void* {
        void* p = ws + off;
        off += (bytes + 255) & ~(size_t)255;
        return p;
    };
    unsigned short* xcat   = (unsigned short*)alloc((size_t)NSEG * KCAT * 2);
    unsigned short* Pt     = (unsigned short*)alloc((size_t)HID * KP1 * 2);
    unsigned short* Wt     = (unsigned short*)alloc((size_t)HID * KCAT * 2);
    int*            deg    = (int*)alloc((size_t)NSEG * 4);
    float*          dinv   = (float*)alloc((size_t)NSEG * 4);
    int*            cnt    = (int*)alloc((size_t)NSEG * 4);
    int*            rowptr = (int*)alloc((size_t)(NSEG + 1) * 4);
    int*            cursor = (int*)alloc((size_t)NSEG * 4);
    long long*      colval = (long long*)alloc((size_t)NEDGE * 8);
    int*            bsum   = (int*)alloc((size_t)NBLK * 4);
    int*            boff   = (int*)alloc((size_t)NBLK * 4);
    int*            flag   = (int*)alloc(256);
    if (off > ws_size) return;

    hipMemsetAsync(deg, 0, (size_t)NSEG * 4, stream);
    hipMemsetAsync(cnt, 0, (size_t)NSEG * 4, stream);

    detect_kernel<<<1, 64, 0, stream>>>((const unsigned int*)E, flag);
    prep_pt_kernel<<<HID, 256, 0, stream>>>(P, Pt);
    prep_wt_kernel<<<HID, 256, 0, stream>>>(W, Wt);

    deg_cnt_kernel<<<NEDGE / 256, 256, 0, stream>>>(E, flag, deg, cnt);
    dinv_kernel<<<(NSEG + 255) / 256, 256, 0, stream>>>(deg, dinv);
    scan1_kernel<<<NBLK, 256, 0, stream>>>(cnt, bsum);
    scan2_kernel<<<1, 256, 0, stream>>>(bsum, boff, rowptr);
    scan3_kernel<<<NBLK, 256, 0, stream>>>(cnt, boff, rowptr, cursor);
    scatter_kernel<<<NEDGE / 256, 256, 0, stream>>>(E, flag, dinv, cursor, colval);

    gemm1_kernel<<<NSEG / 64, 256, 0, stream>>>(S, Pt, raw, xcat);

    // column-tiled props: grid = 4 passes x (NSEG/4) node-groups
    prop_kernel<<<NSEG, 256, 0, stream>>>(xcat, rowptr, colval, 0 * HID, 1 * HID, -1, 1.f);
    prop_kernel<<<NSEG, 256, 0, stream>>>(xcat, rowptr, colval, 1 * HID, 2 * HID, 0 * HID, 2.f);
    prop_kernel<<<NSEG, 256, 0, stream>>>(xcat, rowptr, colval, 2 * HID, 3 * HID, 1 * HID, 2.f);
    prop_kernel<<<NSEG, 256, 0, stream>>>(xcat, rowptr, colval, 3 * HID, 4 * HID, 2 * HID, 2.f);

    gemm2_kernel<<<(NSEG + 127) / 128, 512, 0, stream>>>(xcat, Wt, bias, gamma, beta, out);
}

// Round 11
// 431.533 us; speedup vs baseline: 1.3153x; 1.3153x over previous
//
#include <hip/hip_runtime.h>

#define NSEG 40000
#define NREG 1000
#define NEDGE 640000
#define HID 256
#define KCAT 1280   // 5 * HID
#define KP1 1024    // padded K stride for Pt (cols 1000..1023 zero)
#define LPAD 40     // LDS row stride (bf16) for gemm1 tiles
#define NBLK 157    // ceil(NSEG/256)

typedef float f32x4 __attribute__((ext_vector_type(4)));
typedef short s16x8 __attribute__((ext_vector_type(8)));
typedef unsigned short u16x4 __attribute__((ext_vector_type(4)));
typedef unsigned short u16x8 __attribute__((ext_vector_type(8)));

typedef __attribute__((address_space(3))) unsigned int lds_u32;
typedef __attribute__((address_space(1))) const unsigned int glb_u32;

__device__ __forceinline__ void dma16(const void* g, void* l) {
    // per-lane GLOBAL src; wave-uniform LDS base, HW writes lane i at base+i*16.
    __builtin_amdgcn_global_load_lds((glb_u32*)g, (lds_u32*)l, 16, 0, 0);
}

__device__ __forceinline__ unsigned short f2bf(float f) {
    unsigned u = __builtin_bit_cast(unsigned, f);
    u += 0x7FFFu + ((u >> 16) & 1u);   // round-to-nearest-even
    return (unsigned short)(u >> 16);
}
__device__ __forceinline__ float bf2f(unsigned short h) {
    unsigned u = ((unsigned)h) << 16;
    return __builtin_bit_cast(float, u);
}

__device__ __forceinline__ f32x4 mfma16(s16x8 a, s16x8 b, f32x4 c) {
    return __builtin_amdgcn_mfma_f32_16x16x32_bf16(a, b, c, 0, 0, 0);
}

// ---------------------------------------------------------------- edge dtype
__global__ void detect_kernel(const unsigned int* __restrict__ E, int* flag) {
    int lane = threadIdx.x;
    unsigned v = E[2 * lane + 1];
    unsigned long long m = __ballot(v == 0u);
    if (lane == 0) *flag = (__popcll(m) >= 48) ? 1 : 0;
}

__device__ __forceinline__ int edge_at(const void* E, int idx, int is64) {
    return is64 ? (int)((const long long*)E)[idx] : ((const int*)E)[idx];
}

// ---------------------------------------------------------------- CSR build
__global__ __launch_bounds__(256) void deg_cnt_kernel(const void* __restrict__ E,
                                                      const int* __restrict__ flag,
                                                      int* deg, int* cnt) {
    int e = blockIdx.x * 256 + threadIdx.x;
    if (e >= NEDGE) return;
    int is64 = *flag;
    int s = edge_at(E, e, is64);
    int d = edge_at(E, e + NEDGE, is64);
    if (s != d) {
        atomicAdd(&deg[s], 1);
        atomicAdd(&cnt[d], 1);
    }
}

__global__ __launch_bounds__(256) void dinv_kernel(const int* __restrict__ deg,
                                                   float* __restrict__ dinv) {
    int i = blockIdx.x * 256 + threadIdx.x;
    if (i < NSEG) {
        int d = deg[i];
        dinv[i] = d > 0 ? rsqrtf((float)d) : 0.f;
    }
}

// --- hierarchical scan
__global__ __launch_bounds__(256) void scan1_kernel(const int* __restrict__ cnt,
                                                    int* __restrict__ bsum) {
    __shared__ int sh[256];
    int t = threadIdx.x;
    int i = blockIdx.x * 256 + t;
    sh[t] = (i < NSEG) ? cnt[i] : 0;
    __syncthreads();
    for (int o = 128; o > 0; o >>= 1) {
        if (t < o) sh[t] += sh[t + o];
        __syncthreads();
    }
    if (t == 0) bsum[blockIdx.x] = sh[0];
}

__global__ __launch_bounds__(256) void scan2_kernel(const int* __restrict__ bsum,
                                                    int* __restrict__ boff,
                                                    int* __restrict__ rowptr) {
    __shared__ int sh[256];
    int t = threadIdx.x;
    int v = (t < NBLK) ? bsum[t] : 0;
    sh[t] = v;
    __syncthreads();
    for (int o = 1; o < 256; o <<= 1) {
        int x = 0;
        if (t >= o) x = sh[t - o];
        __syncthreads();
        if (t >= o) sh[t] += x;
        __syncthreads();
    }
    if (t < NBLK) boff[t] = sh[t] - v;
    if (t == 255) rowptr[NSEG] = sh[255];
}

__global__ __launch_bounds__(256) void scan3_kernel(const int* __restrict__ cnt,
                                                    const int* __restrict__ boff,
                                                    int* __restrict__ rowptr,
                                                    int* __restrict__ cursor) {
    __shared__ int sh[256];
    int t = threadIdx.x;
    int i = blockIdx.x * 256 + t;
    int v = (i < NSEG) ? cnt[i] : 0;
    sh[t] = v;
    __syncthreads();
    for (int o = 1; o < 256; o <<= 1) {
        int x = 0;
        if (t >= o) x = sh[t - o];
        __syncthreads();
        if (t >= o) sh[t] += x;
        __syncthreads();
    }
    if (i < NSEG) {
        int p = boff[blockIdx.x] + sh[t] - v;
        rowptr[i] = p;
        cursor[i] = p;
    }
}

// writes fused (colidx, val-bits) 8B records
__global__ __launch_bounds__(256) void scatter_kernel(const void* __restrict__ E,
                                                      const int* __restrict__ flag,
                                                      const float* __restrict__ dinv,
                                                      int* cursor,
                                                      long long* __restrict__ colval) {
    int e = blockIdx.x * 256 + threadIdx.x;
    if (e >= NEDGE) return;
    int is64 = *flag;
    int s = edge_at(E, e, is64);
    int d = edge_at(E, e + NEDGE, is64);
    if (s != d) {
        int pos = atomicAdd(&cursor[d], 1);
        float v = -dinv[s] * dinv[d];
        colval[pos] = ((long long)(unsigned)__builtin_bit_cast(unsigned, v) << 32)
                    | (unsigned)s;
    }
}

// ---------------------------------------------------------------- weight prep (fused)
__global__ void prep_w_kernel(const float* __restrict__ P, const float* __restrict__ W,
                              unsigned short* __restrict__ Pt, unsigned short* __restrict__ Wt) {
    int n = blockIdx.x;
    for (int k = threadIdx.x; k < KP1; k += blockDim.x)
        Pt[(size_t)n * KP1 + k] = (k < NREG) ? f2bf(P[(size_t)k * HID + n]) : (unsigned short)0;
    for (int k = threadIdx.x; k < KCAT; k += blockDim.x)
        Wt[(size_t)n * KCAT + k] = f2bf(W[(size_t)k * HID + n]);
}

// ---------------------------------------------------------------- GEMM1 (R9-exact: 93-96us)
__global__ __launch_bounds__(256) void gemm1_kernel(const float* __restrict__ S,
                                                    const unsigned short* __restrict__ Pt,
                                                    float* __restrict__ raw,
                                                    unsigned short* __restrict__ xcat) {
    __shared__ unsigned short As[64][LPAD];
    __shared__ unsigned short Bs[256][LPAD];
    const int m0 = blockIdx.x * 64;
    const int tid = threadIdx.x;
    const int lane = tid & 63, wn = tid >> 6;
    const int r = lane & 15, q = lane >> 4;
    const int srow = tid >> 2, scol = (tid & 3) * 8;

    f32x4 acc[4][4] = {};

    for (int kb = 0; kb < NREG; kb += 32) {
        const bool kvalid = (kb + scol + 8 <= NREG);  // NREG % 8 == 0
        u16x8 av = {0, 0, 0, 0, 0, 0, 0, 0};
        u16x8 bv0 = av, bv1 = av, bv2 = av, bv3 = av;
        if (kvalid) {
            const float* sp = S + (size_t)(m0 + srow) * NREG + kb + scol;
            f32x4 f0 = *(const f32x4*)sp;
            f32x4 f1 = *(const f32x4*)(sp + 4);
            av[0] = f2bf(f0[0]); av[1] = f2bf(f0[1]); av[2] = f2bf(f0[2]); av[3] = f2bf(f0[3]);
            av[4] = f2bf(f1[0]); av[5] = f2bf(f1[1]); av[6] = f2bf(f1[2]); av[7] = f2bf(f1[3]);
            bv0 = *(const u16x8*)(Pt + (size_t)(srow)       * KP1 + kb + scol);
            bv1 = *(const u16x8*)(Pt + (size_t)(srow +  64) * KP1 + kb + scol);
            bv2 = *(const u16x8*)(Pt + (size_t)(srow + 128) * KP1 + kb + scol);
            bv3 = *(const u16x8*)(Pt + (size_t)(srow + 192) * KP1 + kb + scol);
        }
        __syncthreads();
        *(u16x8*)&As[srow][scol] = av;
        *(u16x8*)&Bs[srow][scol] = bv0;
        *(u16x8*)&Bs[srow + 64][scol] = bv1;
        *(u16x8*)&Bs[srow + 128][scol] = bv2;
        *(u16x8*)&Bs[srow + 192][scol] = bv3;
        __syncthreads();
        s16x8 af[4], bfv[4];
#pragma unroll
        for (int am = 0; am < 4; ++am) af[am] = *(const s16x8*)&As[am * 16 + r][q * 8];
#pragma unroll
        for (int bn = 0; bn < 4; ++bn) bfv[bn] = *(const s16x8*)&Bs[wn * 64 + bn * 16 + r][q * 8];
#pragma unroll
        for (int am = 0; am < 4; ++am) {
#pragma unroll
            for (int bn = 0; bn < 4; ++bn)
                acc[am][bn] = mfma16(af[am], bfv[bn], acc[am][bn]);
        }
    }
#pragma unroll
    for (int am = 0; am < 4; ++am) {
        int rowb = m0 + am * 16 + q * 4;
#pragma unroll
        for (int bn = 0; bn < 4; ++bn) {
            int col = wn * 64 + bn * 16 + r;
#pragma unroll
            for (int i = 0; i < 4; ++i) {
                float v = acc[am][bn][i];
                raw[(size_t)(rowb + i) * HID + col] = v;
                xcat[(size_t)(rowb + i) * KCAT + col] = f2bf(v);
            }
        }
    }
}

// ---------------------------------------------------------------- propagation (half-wave gather)
// One wave per node. 32 lanes x u16x8 = full 512B row per edge -> each gather
// instruction serves 2 edges (1KB/wave). 8 named accumulators per lane;
// cross-half combine via shfl_xor(32); half0 stores the row.
__global__ __launch_bounds__(256) void prop_kernel(unsigned short* xcat,
                                                   const int* __restrict__ rowptr,
                                                   const long long* __restrict__ colval,
                                                   int inOff, int outOff, int subOff,
                                                   float scale) {
    const int g = blockIdx.x * 4 + (threadIdx.x >> 6);
    const int lane = threadIdx.x & 63;
    const int half = lane >> 5;
    const int l5 = lane & 31;
    const int e0 = rowptr[g], e1 = rowptr[g + 1];
    float a0 = 0.f, a1 = 0.f, a2 = 0.f, a3 = 0.f;
    float a4 = 0.f, a5 = 0.f, a6 = 0.f, a7 = 0.f;
    const unsigned short* xin = xcat + inOff + l5 * 8;

    for (int base = e0; base < e1; base += 64) {
        int m = e1 - base;
        if (m > 64) m = 64;
        int cc = 0;
        float vv = 0.f;
        if (lane < m) {
            long long cv = colval[base + lane];
            cc = (int)(unsigned)cv;
            vv = __builtin_bit_cast(float, (unsigned)(cv >> 32));
        }
        int i = 0;
#pragma unroll 4
        for (; i + 2 <= m; i += 2) {
            int c = __shfl(cc, i + half);
            float v = __shfl(vv, i + half);
            u16x8 t = *(const u16x8*)(xin + (size_t)c * KCAT);
            a0 += v * bf2f(t[0]); a1 += v * bf2f(t[1]);
            a2 += v * bf2f(t[2]); a3 += v * bf2f(t[3]);
            a4 += v * bf2f(t[4]); a5 += v * bf2f(t[5]);
            a6 += v * bf2f(t[6]); a7 += v * bf2f(t[7]);
        }
        if (i < m) {   // odd tail: half0 handles the last edge
            int c = __shfl(cc, i);
            float v = __shfl(vv, i);
            if (half == 0) {
                u16x8 t = *(const u16x8*)(xin + (size_t)c * KCAT);
                a0 += v * bf2f(t[0]); a1 += v * bf2f(t[1]);
                a2 += v * bf2f(t[2]); a3 += v * bf2f(t[3]);
                a4 += v * bf2f(t[4]); a5 += v * bf2f(t[5]);
                a6 += v * bf2f(t[6]); a7 += v * bf2f(t[7]);
            }
        }
    }
    // combine halves (edges were split even/odd across halves)
    a0 += __shfl_xor(a0, 32); a1 += __shfl_xor(a1, 32);
    a2 += __shfl_xor(a2, 32); a3 += __shfl_xor(a3, 32);
    a4 += __shfl_xor(a4, 32); a5 += __shfl_xor(a5, 32);
    a6 += __shfl_xor(a6, 32); a7 += __shfl_xor(a7, 32);

    if (half == 0) {
        a0 *= scale; a1 *= scale; a2 *= scale; a3 *= scale;
        a4 *= scale; a5 *= scale; a6 *= scale; a7 *= scale;
        if (subOff >= 0) {
            u16x8 p = *(const u16x8*)(xcat + (size_t)g * KCAT + subOff + l5 * 8);
            a0 -= bf2f(p[0]); a1 -= bf2f(p[1]); a2 -= bf2f(p[2]); a3 -= bf2f(p[3]);
            a4 -= bf2f(p[4]); a5 -= bf2f(p[5]); a6 -= bf2f(p[6]); a7 -= bf2f(p[7]);
        }
        u16x8 o = {f2bf(a0), f2bf(a1), f2bf(a2), f2bf(a3),
                   f2bf(a4), f2bf(a5), f2bf(a6), f2bf(a7)};
        *(u16x8*)(xcat + (size_t)g * KCAT + outOff + l5 * 8) = o;
    }
}

// ---------------------------------------------------------------- GEMM2 + GELU + LN (R9-exact, BM=128 dbuf-DMA)
__global__ __launch_bounds__(512) void gemm2_kernel(const unsigned short* __restrict__ xcat,
                                                    const unsigned short* __restrict__ Wt,
                                                    const float* __restrict__ bias,
                                                    const float* __restrict__ gamma,
                                                    const float* __restrict__ beta,
                                                    float* __restrict__ outp) {
    __shared__ unsigned short As[2][128 * 32];
    __shared__ unsigned short Bs[2][256 * 32];
    __shared__ float rs[128][4];
    __shared__ float rss[128][4];
    const int tid = threadIdx.x;
    const int lane = tid & 63, wid = tid >> 6;
    const int wm = wid >> 2, wn = wid & 3;
    const int r = lane & 15, q = lane >> 4;
    const int qx8 = (q ^ (r & 3)) << 3;
    const int m0 = blockIdx.x * 128;
    const int crow = lane >> 2;
    const int bcol = (((lane & 3) ^ ((lane >> 2) & 3)) << 3);

    f32x4 acc[4][4] = {};

    // 24 chunks/buffer: 0..15 = B (Wt rows), 16..23 = A (xcat rows m0+..).
    auto stage = [&](int c, int kb) {
#pragma unroll
        for (int k = 0; k < 3; ++k) {
            int idx = 3 * wid + k;
            if (idx < 16) {
                int n = idx * 16 + crow;
                dma16(Wt + (size_t)n * KCAT + kb + bcol, &Bs[c][idx * 512]);
            } else {
                int a = idx - 16;
                int row = m0 + a * 16 + crow;   // tail reads past xcat land in ws: safe, store-guarded
                dma16(xcat + (size_t)row * KCAT + kb + bcol, &As[c][a * 512]);
            }
        }
    };

    stage(0, 0);
    __syncthreads();

    for (int t = 0; t < 40; ++t) {
        const int c = t & 1;
        if (t < 39) stage(c ^ 1, (t + 1) * 32);
        s16x8 af[4], bfv[4];
#pragma unroll
        for (int am = 0; am < 4; ++am)
            af[am] = *(const s16x8*)&As[c][(wm * 64 + am * 16 + r) * 32 + qx8];
#pragma unroll
        for (int bn = 0; bn < 4; ++bn)
            bfv[bn] = *(const s16x8*)&Bs[c][(wn * 64 + bn * 16 + r) * 32 + qx8];
#pragma unroll
        for (int am = 0; am < 4; ++am)
#pragma unroll
            for (int bn = 0; bn < 4; ++bn)
                acc[am][bn] = mfma16(af[am], bfv[bn], acc[am][bn]);
        __syncthreads();
    }

    // epilogue: bias + exact GELU, row stats, LN, store
    float bc[4], gm[4], bt[4];
#pragma unroll
    for (int bn = 0; bn < 4; ++bn) {
        int col = wn * 64 + bn * 16 + r;
        bc[bn] = bias[col];
        gm[bn] = gamma[col];
        bt[bn] = beta[col];
    }
#pragma unroll
    for (int am = 0; am < 4; ++am) {
#pragma unroll
        for (int i = 0; i < 4; ++i) {
            float s = 0.f, ss = 0.f;
#pragma unroll
            for (int bn = 0; bn < 4; ++bn) {
                float v = acc[am][bn][i] + bc[bn];
                v = 0.5f * v * (1.f + erff(v * 0.70710678118654752f));
                acc[am][bn][i] = v;
                s += v;
                ss += v * v;
            }
#pragma unroll
            for (int msk = 1; msk < 16; msk <<= 1) {
                s += __shfl_xor(s, msk);
                ss += __shfl_xor(ss, msk);
            }
            if (r == 0) {
                int row = wm * 64 + am * 16 + q * 4 + i;
                rs[row][wn] = s;
                rss[row][wn] = ss;
            }
        }
    }
    __syncthreads();
#pragma unroll
    for (int am = 0; am < 4; ++am) {
#pragma unroll
        for (int i = 0; i < 4; ++i) {
            int row = wm * 64 + am * 16 + q * 4 + i;
            float s = rs[row][0] + rs[row][1] + rs[row][2] + rs[row][3];
            float ss = rss[row][0] + rss[row][1] + rss[row][2] + rss[row][3];
            float mu = s * (1.f / HID);
            float var = ss * (1.f / HID) - mu * mu;
            float inv = rsqrtf(var + 1e-5f);
            if (m0 + row < NSEG) {
#pragma unroll
                for (int bn = 0; bn < 4; ++bn) {
                    int col = wn * 64 + bn * 16 + r;
                    outp[(size_t)(m0 + row) * HID + col] = (acc[am][bn][i] - mu) * inv * gm[bn] + bt[bn];
                }
            }
        }
    }
}

// ---------------------------------------------------------------- launch
extern "C" void kernel_launch(void* const* d_in, const int* in_sizes, int n_in,
                              void* d_out, int out_size, void* d_ws, size_t ws_size,
                              hipStream_t stream) {
    const float* P     = (const float*)d_in[0];
    const float* S     = (const float*)d_in[1];
    const void*  E     = d_in[2];
    const float* W     = (const float*)d_in[3];
    const float* bias  = (const float*)d_in[4];
    const float* gamma = (const float*)d_in[5];
    const float* beta  = (const float*)d_in[6];

    float* out = (float*)d_out;            // seg_low [40000*256]
    float* raw = out + (size_t)NSEG * HID; // seg_low_raw [40000*256]

    char* ws = (char*)d_ws;
    size_t off = 0;
    auto alloc = [&](size_t bytes) -> void* {
        void* p = ws + off;
        off += (bytes + 255) & ~(size_t)255;
        return p;
    };
    unsigned short* xcat   = (unsigned short*)alloc((size_t)NSEG * KCAT * 2);
    unsigned short* Pt     = (unsigned short*)alloc((size_t)HID * KP1 * 2);
    unsigned short* Wt     = (unsigned short*)alloc((size_t)HID * KCAT * 2);
    int*            deg    = (int*)alloc((size_t)NSEG * 4);
    float*          dinv   = (float*)alloc((size_t)NSEG * 4);
    int*            cnt    = (int*)alloc((size_t)NSEG * 4);
    int*            rowptr = (int*)alloc((size_t)(NSEG + 1) * 4);
    int*            cursor = (int*)alloc((size_t)NSEG * 4);
    long long*      colval = (long long*)alloc((size_t)NEDGE * 8);
    int*            bsum   = (int*)alloc((size_t)NBLK * 4);
    int*            boff   = (int*)alloc((size_t)NBLK * 4);
    int*            flag   = (int*)alloc(256);
    if (off > ws_size) return;

    hipMemsetAsync(deg, 0, (size_t)NSEG * 4, stream);
    hipMemsetAsync(cnt, 0, (size_t)NSEG * 4, stream);

    detect_kernel<<<1, 64, 0, stream>>>((const unsigned int*)E, flag);
    prep_w_kernel<<<HID, 256, 0, stream>>>(P, W, Pt, Wt);

    deg_cnt_kernel<<<NEDGE / 256, 256, 0, stream>>>(E, flag, deg, cnt);
    dinv_kernel<<<(NSEG + 255) / 256, 256, 0, stream>>>(deg, dinv);
    scan1_kernel<<<NBLK, 256, 0, stream>>>(cnt, bsum);
    scan2_kernel<<<1, 256, 0, stream>>>(bsum, boff, rowptr);
    scan3_kernel<<<NBLK, 256, 0, stream>>>(cnt, boff, rowptr, cursor);
    scatter_kernel<<<NEDGE / 256, 256, 0, stream>>>(E, flag, dinv, cursor, colval);

    gemm1_kernel<<<NSEG / 64, 256, 0, stream>>>(S, Pt, raw, xcat);

    prop_kernel<<<NSEG / 4, 256, 0, stream>>>(xcat, rowptr, colval, 0 * HID, 1 * HID, -1, 1.f);
    prop_kernel<<<NSEG / 4, 256, 0, stream>>>(xcat, rowptr, colval, 1 * HID, 2 * HID, 0 * HID, 2.f);
    prop_kernel<<<NSEG / 4, 256, 0, stream>>>(xcat, rowptr, colval, 2 * HID, 3 * HID, 1 * HID, 2.f);
    prop_kernel<<<NSEG / 4, 256, 0, stream>>>(xcat, rowptr, colval, 3 * HID, 4 * HID, 2 * HID, 2.f);

    gemm2_kernel<<<(NSEG + 127) / 128, 512, 0, stream>>>(xcat, Wt, bias, gamma, beta, out);
}

// Round 12
// 385.519 us; speedup vs baseline: 1.4723x; 1.1194x over previous
//
#include <hip/hip_runtime.h>

#define NSEG 40000
#define NREG 1000
#define NEDGE 640000
#define HID 256
#define KCAT 1280   // 5 * HID
#define KP1 1024    // padded K stride for Pt (cols 1000..1023 zero)
#define LPAD 40     // LDS row stride (bf16) for gemm1 tiles
#define NBLK 157    // ceil(NSEG/256)

typedef float f32x4 __attribute__((ext_vector_type(4)));
typedef float f32x2 __attribute__((ext_vector_type(2)));
typedef short s16x8 __attribute__((ext_vector_type(8)));
typedef unsigned short u16x4 __attribute__((ext_vector_type(4)));
typedef unsigned short u16x8 __attribute__((ext_vector_type(8)));
typedef unsigned int u32x2 __attribute__((ext_vector_type(2)));

typedef __attribute__((address_space(3))) unsigned int lds_u32;
typedef __attribute__((address_space(1))) const unsigned int glb_u32;

__device__ __forceinline__ void dma16(const void* g, void* l) {
    // per-lane GLOBAL src; wave-uniform LDS base, HW writes lane i at base+i*16.
    __builtin_amdgcn_global_load_lds((glb_u32*)g, (lds_u32*)l, 16, 0, 0);
}

__device__ __forceinline__ unsigned short f2bf(float f) {
    unsigned u = __builtin_bit_cast(unsigned, f);
    u += 0x7FFFu + ((u >> 16) & 1u);   // round-to-nearest-even
    return (unsigned short)(u >> 16);
}
__device__ __forceinline__ float bf2f(unsigned short h) {
    unsigned u = ((unsigned)h) << 16;
    return __builtin_bit_cast(float, u);
}
__device__ __forceinline__ unsigned char f2fp8(float v) {
    return (unsigned char)__builtin_amdgcn_cvt_pk_fp8_f32(v, v, 0, false);
}

__device__ __forceinline__ f32x4 mfma16(s16x8 a, s16x8 b, f32x4 c) {
    return __builtin_amdgcn_mfma_f32_16x16x32_bf16(a, b, c, 0, 0, 0);
}

// ---------------------------------------------------------------- edge dtype
__global__ void detect_kernel(const unsigned int* __restrict__ E, int* flag) {
    int lane = threadIdx.x;
    unsigned v = E[2 * lane + 1];
    unsigned long long m = __ballot(v == 0u);
    if (lane == 0) *flag = (__popcll(m) >= 48) ? 1 : 0;
}

__device__ __forceinline__ int edge_at(const void* E, int idx, int is64) {
    return is64 ? (int)((const long long*)E)[idx] : ((const int*)E)[idx];
}

// ---------------------------------------------------------------- CSR build
__global__ __launch_bounds__(256) void deg_cnt_kernel(const void* __restrict__ E,
                                                      const int* __restrict__ flag,
                                                      int* deg, int* cnt) {
    int e = blockIdx.x * 256 + threadIdx.x;
    if (e >= NEDGE) return;
    int is64 = *flag;
    int s = edge_at(E, e, is64);
    int d = edge_at(E, e + NEDGE, is64);
    if (s != d) {
        atomicAdd(&deg[s], 1);
        atomicAdd(&cnt[d], 1);
    }
}

// --- hierarchical scan (scan1 also computes dinv)
__global__ __launch_bounds__(256) void scan1_kernel(const int* __restrict__ cnt,
                                                    const int* __restrict__ deg,
                                                    float* __restrict__ dinv,
                                                    int* __restrict__ bsum) {
    __shared__ int sh[256];
    int t = threadIdx.x;
    int i = blockIdx.x * 256 + t;
    int c = (i < NSEG) ? cnt[i] : 0;
    sh[t] = c;
    if (i < NSEG) {
        int d = deg[i];
        dinv[i] = d > 0 ? rsqrtf((float)d) : 0.f;
    }
    __syncthreads();
    for (int o = 128; o > 0; o >>= 1) {
        if (t < o) sh[t] += sh[t + o];
        __syncthreads();
    }
    if (t == 0) bsum[blockIdx.x] = sh[0];
}

__global__ __launch_bounds__(256) void scan2_kernel(const int* __restrict__ bsum,
                                                    int* __restrict__ boff,
                                                    int* __restrict__ rowptr) {
    __shared__ int sh[256];
    int t = threadIdx.x;
    int v = (t < NBLK) ? bsum[t] : 0;
    sh[t] = v;
    __syncthreads();
    for (int o = 1; o < 256; o <<= 1) {
        int x = 0;
        if (t >= o) x = sh[t - o];
        __syncthreads();
        if (t >= o) sh[t] += x;
        __syncthreads();
    }
    if (t < NBLK) boff[t] = sh[t] - v;
    if (t == 255) rowptr[NSEG] = sh[255];
}

__global__ __launch_bounds__(256) void scan3_kernel(const int* __restrict__ cnt,
                                                    const int* __restrict__ boff,
                                                    int* __restrict__ rowptr,
                                                    int* __restrict__ cursor) {
    __shared__ int sh[256];
    int t = threadIdx.x;
    int i = blockIdx.x * 256 + t;
    int v = (i < NSEG) ? cnt[i] : 0;
    sh[t] = v;
    __syncthreads();
    for (int o = 1; o < 256; o <<= 1) {
        int x = 0;
        if (t >= o) x = sh[t - o];
        __syncthreads();
        if (t >= o) sh[t] += x;
        __syncthreads();
    }
    if (i < NSEG) {
        int p = boff[blockIdx.x] + sh[t] - v;
        rowptr[i] = p;
        cursor[i] = p;
    }
}

// writes fused (colidx, val-bits) 8B records
__global__ __launch_bounds__(256) void scatter_kernel(const void* __restrict__ E,
                                                      const int* __restrict__ flag,
                                                      const float* __restrict__ dinv,
                                                      int* cursor,
                                                      long long* __restrict__ colval) {
    int e = blockIdx.x * 256 + threadIdx.x;
    if (e >= NEDGE) return;
    int is64 = *flag;
    int s = edge_at(E, e, is64);
    int d = edge_at(E, e + NEDGE, is64);
    if (s != d) {
        int pos = atomicAdd(&cursor[d], 1);
        float v = -dinv[s] * dinv[d];
        colval[pos] = ((long long)(unsigned)__builtin_bit_cast(unsigned, v) << 32)
                    | (unsigned)s;
    }
}

// ---------------------------------------------------------------- weight prep (fused)
__global__ void prep_w_kernel(const float* __restrict__ P, const float* __restrict__ W,
                              unsigned short* __restrict__ Pt, unsigned short* __restrict__ Wt) {
    int n = blockIdx.x;
    for (int k = threadIdx.x; k < KP1; k += blockDim.x)
        Pt[(size_t)n * KP1 + k] = (k < NREG) ? f2bf(P[(size_t)k * HID + n]) : (unsigned short)0;
    for (int k = threadIdx.x; k < KCAT; k += blockDim.x)
        Wt[(size_t)n * KCAT + k] = f2bf(W[(size_t)k * HID + n]);
}

// ---------------------------------------------------------------- GEMM1 (R9 structure + fp8 side-write)
__global__ __launch_bounds__(256) void gemm1_kernel(const float* __restrict__ S,
                                                    const unsigned short* __restrict__ Pt,
                                                    float* __restrict__ raw,
                                                    unsigned short* __restrict__ xcat,
                                                    unsigned char* __restrict__ x8) {
    __shared__ unsigned short As[64][LPAD];
    __shared__ unsigned short Bs[256][LPAD];
    const int m0 = blockIdx.x * 64;
    const int tid = threadIdx.x;
    const int lane = tid & 63, wn = tid >> 6;
    const int r = lane & 15, q = lane >> 4;
    const int srow = tid >> 2, scol = (tid & 3) * 8;

    f32x4 acc[4][4] = {};

    for (int kb = 0; kb < NREG; kb += 32) {
        const bool kvalid = (kb + scol + 8 <= NREG);  // NREG % 8 == 0
        u16x8 av = {0, 0, 0, 0, 0, 0, 0, 0};
        u16x8 bv0 = av, bv1 = av, bv2 = av, bv3 = av;
        if (kvalid) {
            const float* sp = S + (size_t)(m0 + srow) * NREG + kb + scol;
            f32x4 f0 = *(const f32x4*)sp;
            f32x4 f1 = *(const f32x4*)(sp + 4);
            av[0] = f2bf(f0[0]); av[1] = f2bf(f0[1]); av[2] = f2bf(f0[2]); av[3] = f2bf(f0[3]);
            av[4] = f2bf(f1[0]); av[5] = f2bf(f1[1]); av[6] = f2bf(f1[2]); av[7] = f2bf(f1[3]);
            bv0 = *(const u16x8*)(Pt + (size_t)(srow)       * KP1 + kb + scol);
            bv1 = *(const u16x8*)(Pt + (size_t)(srow +  64) * KP1 + kb + scol);
            bv2 = *(const u16x8*)(Pt + (size_t)(srow + 128) * KP1 + kb + scol);
            bv3 = *(const u16x8*)(Pt + (size_t)(srow + 192) * KP1 + kb + scol);
        }
        __syncthreads();
        *(u16x8*)&As[srow][scol] = av;
        *(u16x8*)&Bs[srow][scol] = bv0;
        *(u16x8*)&Bs[srow + 64][scol] = bv1;
        *(u16x8*)&Bs[srow + 128][scol] = bv2;
        *(u16x8*)&Bs[srow + 192][scol] = bv3;
        __syncthreads();
        s16x8 af[4], bfv[4];
#pragma unroll
        for (int am = 0; am < 4; ++am) af[am] = *(const s16x8*)&As[am * 16 + r][q * 8];
#pragma unroll
        for (int bn = 0; bn < 4; ++bn) bfv[bn] = *(const s16x8*)&Bs[wn * 64 + bn * 16 + r][q * 8];
#pragma unroll
        for (int am = 0; am < 4; ++am) {
#pragma unroll
            for (int bn = 0; bn < 4; ++bn)
                acc[am][bn] = mfma16(af[am], bfv[bn], acc[am][bn]);
        }
    }
#pragma unroll
    for (int am = 0; am < 4; ++am) {
        int rowb = m0 + am * 16 + q * 4;
#pragma unroll
        for (int bn = 0; bn < 4; ++bn) {
            int col = wn * 64 + bn * 16 + r;
#pragma unroll
            for (int i = 0; i < 4; ++i) {
                float v = acc[am][bn][i];
                raw[(size_t)(rowb + i) * HID + col] = v;
                xcat[(size_t)(rowb + i) * KCAT + col] = f2bf(v);
                x8[(size_t)(rowb + i) * KCAT + col] = f2fp8(v);
            }
        }
    }
}

// ---------------------------------------------------------------- propagation (half-wave, fp8 gather)
// 32 lanes x 8 fp8 bytes = full 256B row per edge -> 2 edges/gather-instr/wave.
// Gather input fp8 (halved bytes); outputs written bf16 (gemm2/sub) + fp8 (next prop).
__global__ __launch_bounds__(256) void prop_kernel(unsigned short* xcat,
                                                   unsigned char* x8,
                                                   const int* __restrict__ rowptr,
                                                   const long long* __restrict__ colval,
                                                   int inOff, int outOff, int subOff,
                                                   float scale, int writeFp8) {
    const int g = blockIdx.x * 4 + (threadIdx.x >> 6);
    const int lane = threadIdx.x & 63;
    const int half = lane >> 5;
    const int l5 = lane & 31;
    const int e0 = rowptr[g], e1 = rowptr[g + 1];
    float a0 = 0.f, a1 = 0.f, a2 = 0.f, a3 = 0.f;
    float a4 = 0.f, a5 = 0.f, a6 = 0.f, a7 = 0.f;
    const unsigned char* xin = x8 + inOff + l5 * 8;

    for (int base = e0; base < e1; base += 64) {
        int m = e1 - base;
        if (m > 64) m = 64;
        int cc = 0;
        float vv = 0.f;
        if (lane < m) {
            long long cv = colval[base + lane];
            cc = (int)(unsigned)cv;
            vv = __builtin_bit_cast(float, (unsigned)(cv >> 32));
        }
        int i = 0;
#pragma unroll 4
        for (; i + 2 <= m; i += 2) {
            int c = __shfl(cc, i + half);
            float v = __shfl(vv, i + half);
            u32x2 t = *(const u32x2*)(xin + (size_t)c * KCAT);
            f32x2 d0 = __builtin_amdgcn_cvt_pk_f32_fp8(t[0], false);
            f32x2 d1 = __builtin_amdgcn_cvt_pk_f32_fp8(t[0], true);
            f32x2 d2 = __builtin_amdgcn_cvt_pk_f32_fp8(t[1], false);
            f32x2 d3 = __builtin_amdgcn_cvt_pk_f32_fp8(t[1], true);
            a0 += v * d0[0]; a1 += v * d0[1];
            a2 += v * d1[0]; a3 += v * d1[1];
            a4 += v * d2[0]; a5 += v * d2[1];
            a6 += v * d3[0]; a7 += v * d3[1];
        }
        if (i < m) {   // odd tail: half0 handles the last edge
            int c = __shfl(cc, i);
            float v = __shfl(vv, i);
            if (half == 0) {
                u32x2 t = *(const u32x2*)(xin + (size_t)c * KCAT);
                f32x2 d0 = __builtin_amdgcn_cvt_pk_f32_fp8(t[0], false);
                f32x2 d1 = __builtin_amdgcn_cvt_pk_f32_fp8(t[0], true);
                f32x2 d2 = __builtin_amdgcn_cvt_pk_f32_fp8(t[1], false);
                f32x2 d3 = __builtin_amdgcn_cvt_pk_f32_fp8(t[1], true);
                a0 += v * d0[0]; a1 += v * d0[1];
                a2 += v * d1[0]; a3 += v * d1[1];
                a4 += v * d2[0]; a5 += v * d2[1];
                a6 += v * d3[0]; a7 += v * d3[1];
            }
        }
    }
    // combine halves (edges split even/odd across halves)
    a0 += __shfl_xor(a0, 32); a1 += __shfl_xor(a1, 32);
    a2 += __shfl_xor(a2, 32); a3 += __shfl_xor(a3, 32);
    a4 += __shfl_xor(a4, 32); a5 += __shfl_xor(a5, 32);
    a6 += __shfl_xor(a6, 32); a7 += __shfl_xor(a7, 32);

    if (half == 0) {
        a0 *= scale; a1 *= scale; a2 *= scale; a3 *= scale;
        a4 *= scale; a5 *= scale; a6 *= scale; a7 *= scale;
        if (subOff >= 0) {   // subtraction operand stays bf16 (accurate)
            u16x8 p = *(const u16x8*)(xcat + (size_t)g * KCAT + subOff + l5 * 8);
            a0 -= bf2f(p[0]); a1 -= bf2f(p[1]); a2 -= bf2f(p[2]); a3 -= bf2f(p[3]);
            a4 -= bf2f(p[4]); a5 -= bf2f(p[5]); a6 -= bf2f(p[6]); a7 -= bf2f(p[7]);
        }
        u16x8 o = {f2bf(a0), f2bf(a1), f2bf(a2), f2bf(a3),
                   f2bf(a4), f2bf(a5), f2bf(a6), f2bf(a7)};
        *(u16x8*)(xcat + (size_t)g * KCAT + outOff + l5 * 8) = o;
        if (writeFp8) {
            unsigned p0 = 0, p1 = 0;
            p0 = __builtin_amdgcn_cvt_pk_fp8_f32(a0, a1, (int)p0, false);
            p0 = __builtin_amdgcn_cvt_pk_fp8_f32(a2, a3, (int)p0, true);
            p1 = __builtin_amdgcn_cvt_pk_fp8_f32(a4, a5, (int)p1, false);
            p1 = __builtin_amdgcn_cvt_pk_fp8_f32(a6, a7, (int)p1, true);
            u32x2 o8 = {p0, p1};
            *(u32x2*)(x8 + (size_t)g * KCAT + outOff + l5 * 8) = o8;
        }
    }
}

// ---------------------------------------------------------------- GEMM2 + GELU + LN (R9-exact, BM=128 dbuf-DMA)
__global__ __launch_bounds__(512) void gemm2_kernel(const unsigned short* __restrict__ xcat,
                                                    const unsigned short* __restrict__ Wt,
                                                    const float* __restrict__ bias,
                                                    const float* __restrict__ gamma,
                                                    const float* __restrict__ beta,
                                                    float* __restrict__ outp) {
    __shared__ unsigned short As[2][128 * 32];
    __shared__ unsigned short Bs[2][256 * 32];
    __shared__ float rs[128][4];
    __shared__ float rss[128][4];
    const int tid = threadIdx.x;
    const int lane = tid & 63, wid = tid >> 6;
    const int wm = wid >> 2, wn = wid & 3;
    const int r = lane & 15, q = lane >> 4;
    const int qx8 = (q ^ (r & 3)) << 3;
    const int m0 = blockIdx.x * 128;
    const int crow = lane >> 2;
    const int bcol = (((lane & 3) ^ ((lane >> 2) & 3)) << 3);

    f32x4 acc[4][4] = {};

    auto stage = [&](int c, int kb) {
#pragma unroll
        for (int k = 0; k < 3; ++k) {
            int idx = 3 * wid + k;
            if (idx < 16) {
                int n = idx * 16 + crow;
                dma16(Wt + (size_t)n * KCAT + kb + bcol, &Bs[c][idx * 512]);
            } else {
                int a = idx - 16;
                int row = m0 + a * 16 + crow;   // tail reads past xcat land in ws: safe, store-guarded
                dma16(xcat + (size_t)row * KCAT + kb + bcol, &As[c][a * 512]);
            }
        }
    };

    stage(0, 0);
    __syncthreads();

    for (int t = 0; t < 40; ++t) {
        const int c = t & 1;
        if (t < 39) stage(c ^ 1, (t + 1) * 32);
        s16x8 af[4], bfv[4];
#pragma unroll
        for (int am = 0; am < 4; ++am)
            af[am] = *(const s16x8*)&As[c][(wm * 64 + am * 16 + r) * 32 + qx8];
#pragma unroll
        for (int bn = 0; bn < 4; ++bn)
            bfv[bn] = *(const s16x8*)&Bs[c][(wn * 64 + bn * 16 + r) * 32 + qx8];
#pragma unroll
        for (int am = 0; am < 4; ++am)
#pragma unroll
            for (int bn = 0; bn < 4; ++bn)
                acc[am][bn] = mfma16(af[am], bfv[bn], acc[am][bn]);
        __syncthreads();
    }

    float bc[4], gm[4], bt[4];
#pragma unroll
    for (int bn = 0; bn < 4; ++bn) {
        int col = wn * 64 + bn * 16 + r;
        bc[bn] = bias[col];
        gm[bn] = gamma[col];
        bt[bn] = beta[col];
    }
#pragma unroll
    for (int am = 0; am < 4; ++am) {
#pragma unroll
        for (int i = 0; i < 4; ++i) {
            float s = 0.f, ss = 0.f;
#pragma unroll
            for (int bn = 0; bn < 4; ++bn) {
                float v = acc[am][bn][i] + bc[bn];
                v = 0.5f * v * (1.f + erff(v * 0.70710678118654752f));
                acc[am][bn][i] = v;
                s += v;
                ss += v * v;
            }
#pragma unroll
            for (int msk = 1; msk < 16; msk <<= 1) {
                s += __shfl_xor(s, msk);
                ss += __shfl_xor(ss, msk);
            }
            if (r == 0) {
                int row = wm * 64 + am * 16 + q * 4 + i;
                rs[row][wn] = s;
                rss[row][wn] = ss;
            }
        }
    }
    __syncthreads();
#pragma unroll
    for (int am = 0; am < 4; ++am) {
#pragma unroll
        for (int i = 0; i < 4; ++i) {
            int row = wm * 64 + am * 16 + q * 4 + i;
            float s = rs[row][0] + rs[row][1] + rs[row][2] + rs[row][3];
            float ss = rss[row][0] + rss[row][1] + rss[row][2] + rss[row][3];
            float mu = s * (1.f / HID);
            float var = ss * (1.f / HID) - mu * mu;
            float inv = rsqrtf(var + 1e-5f);
            if (m0 + row < NSEG) {
#pragma unroll
                for (int bn = 0; bn < 4; ++bn) {
                    int col = wn * 64 + bn * 16 + r;
                    outp[(size_t)(m0 + row) * HID + col] = (acc[am][bn][i] - mu) * inv * gm[bn] + bt[bn];
                }
            }
        }
    }
}

// ---------------------------------------------------------------- launch
extern "C" void kernel_launch(void* const* d_in, const int* in_sizes, int n_in,
                              void* d_out, int out_size, void* d_ws, size_t ws_size,
                              hipStream_t stream) {
    const float* P     = (const float*)d_in[0];
    const float* S     = (const float*)d_in[1];
    const void*  E     = d_in[2];
    const float* W     = (const float*)d_in[3];
    const float* bias  = (const float*)d_in[4];
    const float* gamma = (const float*)d_in[5];
    const float* beta  = (const float*)d_in[6];

    float* out = (float*)d_out;            // seg_low [40000*256]
    float* raw = out + (size_t)NSEG * HID; // seg_low_raw [40000*256]

    char* ws = (char*)d_ws;
    size_t off = 0;
    auto alloc = [&](size_t bytes) -> void* {
        void* p = ws + off;
        off += (bytes + 255) & ~(size_t)255;
        return p;
    };
    unsigned short* xcat   = (unsigned short*)alloc((size_t)NSEG * KCAT * 2);
    unsigned char*  x8     = (unsigned char*)alloc((size_t)NSEG * KCAT);
    unsigned short* Pt     = (unsigned short*)alloc((size_t)HID * KP1 * 2);
    unsigned short* Wt     = (unsigned short*)alloc((size_t)HID * KCAT * 2);
    int*            deg    = (int*)alloc((size_t)NSEG * 4);
    float*          dinv   = (float*)alloc((size_t)NSEG * 4);
    int*            cnt    = (int*)alloc((size_t)NSEG * 4);
    int*            rowptr = (int*)alloc((size_t)(NSEG + 1) * 4);
    int*            cursor = (int*)alloc((size_t)NSEG * 4);
    long long*      colval = (long long*)alloc((size_t)NEDGE * 8);
    int*            bsum   = (int*)alloc((size_t)NBLK * 4);
    int*            boff   = (int*)alloc((size_t)NBLK * 4);
    int*            flag   = (int*)alloc(256);
    if (off > ws_size) return;

    hipMemsetAsync(deg, 0, (size_t)NSEG * 4, stream);
    hipMemsetAsync(cnt, 0, (size_t)NSEG * 4, stream);

    detect_kernel<<<1, 64, 0, stream>>>((const unsigned int*)E, flag);
    prep_w_kernel<<<HID, 256, 0, stream>>>(P, W, Pt, Wt);

    deg_cnt_kernel<<<NEDGE / 256, 256, 0, stream>>>(E, flag, deg, cnt);
    scan1_kernel<<<NBLK, 256, 0, stream>>>(cnt, deg, dinv, bsum);
    scan2_kernel<<<1, 256, 0, stream>>>(bsum, boff, rowptr);
    scan3_kernel<<<NBLK, 256, 0, stream>>>(cnt, boff, rowptr, cursor);
    scatter_kernel<<<NEDGE / 256, 256, 0, stream>>>(E, flag, dinv, cursor, colval);

    gemm1_kernel<<<NSEG / 64, 256, 0, stream>>>(S, Pt, raw, xcat, x8);

    prop_kernel<<<NSEG / 4, 256, 0, stream>>>(xcat, x8, rowptr, colval, 0 * HID, 1 * HID, -1, 1.f, 1);
    prop_kernel<<<NSEG / 4, 256, 0, stream>>>(xcat, x8, rowptr, colval, 1 * HID, 2 * HID, 0 * HID, 2.f, 1);
    prop_kernel<<<NSEG / 4, 256, 0, stream>>>(xcat, x8, rowptr, colval, 2 * HID, 3 * HID, 1 * HID, 2.f, 1);
    prop_kernel<<<NSEG / 4, 256, 0, stream>>>(xcat, x8, rowptr, colval, 3 * HID, 4 * HID, 2 * HID, 2.f, 0);

    gemm2_kernel<<<(NSEG + 127) / 128, 512, 0, stream>>>(xcat, Wt, bias, gamma, beta, out);
}